// Round 10
// baseline (373.351 us; speedup 1.0000x reference)
//
#include <hip/hip_runtime.h>
#include <math.h>

#define SLOPE 0.2f

__device__ __forceinline__ float lrelu(float x) { return x > 0.f ? x : SLOPE * x; }

// bf16 helpers (h is stored bf16 to halve gather traffic; error budget 1e-2)
__device__ __forceinline__ float bflo(unsigned int u) { return __uint_as_float(u << 16); }
__device__ __forceinline__ float bfhi(unsigned int u) { return __uint_as_float(u & 0xffff0000u); }
__device__ __forceinline__ unsigned short f2bf(float f) {   // round-nearest-even
    unsigned int u = __float_as_uint(f);
    unsigned int r = u + 0x7fffu + ((u >> 16) & 1u);
    return (unsigned short)(r >> 16);
}

// ---------------------------------------------------------------------------
// h = x @ W  (CIN=128), fused with attention logits.
// W staged in LDS 32-row panels, double-buffered, register-prefetched one
// panel ahead (R8: per-thread global W loads consumed immediately -> the k
// loop was a latency chain; VALUBusy 37%). Inner loop fully unrolled; all
// hot-loop operands come from LDS.
// ---------------------------------------------------------------------------
template <int COUT, int Hh, int NPT>
__global__ __launch_bounds__(256) void transform_kernel(
    const float* __restrict__ xin, const float* __restrict__ W,
    const float* __restrict__ a_src, const float* __restrict__ a_dst,
    unsigned short* __restrict__ hout, float* __restrict__ alsrc,
    float* __restrict__ aldst, int N)
{
    constexpr int JT = COUT / 4;          // threads per node-group: 32 or 8
    constexpr int GROUPS = 256 / JT;      // node-groups per block: 8 or 32
    constexpr int NB = GROUPS * NPT;      // nodes per block
    constexpr int PAD = 4;
    constexpr int PANEL = 32;             // k-rows per W panel
    constexpr int NPAN = 128 / PANEL;     // 4 panels
    constexpr int WL4 = PANEL * COUT / 1024; // float4 loads/thread/panel: 4 or 1
    __shared__ __align__(16) float xs[NB][128 + PAD];
    __shared__ __align__(16) float wls[2][PANEL][COUT];

    const int node0 = blockIdx.x * NB;
    const int total4 = NB * 32;           // float4s of x to stage
    const int lim4 = (N - node0) * 32;
    const float4* src4 = (const float4*)(xin + (size_t)node0 * 128);
    for (int i = threadIdx.x; i < total4; i += 256) {
        int row = i >> 5, col = i & 31;
        float4 v = (i < lim4) ? src4[i] : make_float4(0.f, 0.f, 0.f, 0.f);
        *(float4*)&xs[row][col << 2] = v;
    }

    const float4* W4 = (const float4*)W;  // row k = COUT/4 float4s
    constexpr int P4 = PANEL * COUT / 4;  // float4s per panel
    {
        float4 t[WL4];
#pragma unroll
        for (int r = 0; r < WL4; ++r) t[r] = W4[threadIdx.x + r * 256];
#pragma unroll
        for (int r = 0; r < WL4; ++r)
            ((float4*)wls[0])[threadIdx.x + r * 256] = t[r];
    }
    __syncthreads();

    const int jt = threadIdx.x % JT;      // 4-wide column group
    const int g  = threadIdx.x / JT;
    const int j4 = jt * 4;

    float4 acc[NPT];
#pragma unroll
    for (int m = 0; m < NPT; ++m) acc[m] = make_float4(0.f, 0.f, 0.f, 0.f);

    for (int p = 0; p < NPAN; ++p) {
        float4 pf[WL4];
        if (p + 1 < NPAN) {
#pragma unroll
            for (int r = 0; r < WL4; ++r)
                pf[r] = W4[(p + 1) * P4 + threadIdx.x + r * 256];
        }
        const int buf = p & 1;
#pragma unroll
        for (int k4 = 0; k4 < PANEL / 4; ++k4) {
            float4 w0 = *(const float4*)&wls[buf][4 * k4 + 0][j4];
            float4 w1 = *(const float4*)&wls[buf][4 * k4 + 1][j4];
            float4 w2 = *(const float4*)&wls[buf][4 * k4 + 2][j4];
            float4 w3 = *(const float4*)&wls[buf][4 * k4 + 3][j4];
#pragma unroll
            for (int m = 0; m < NPT; ++m) {
                float4 xv = *(const float4*)&xs[g * NPT + m][p * PANEL + (k4 << 2)];
                acc[m].x += xv.x * w0.x + xv.y * w1.x + xv.z * w2.x + xv.w * w3.x;
                acc[m].y += xv.x * w0.y + xv.y * w1.y + xv.z * w2.y + xv.w * w3.y;
                acc[m].z += xv.x * w0.z + xv.y * w1.z + xv.z * w2.z + xv.w * w3.z;
                acc[m].w += xv.x * w0.w + xv.y * w1.w + xv.z * w2.w + xv.w * w3.w;
            }
        }
        if (p + 1 < NPAN) {
#pragma unroll
            for (int r = 0; r < WL4; ++r)
                ((float4*)wls[buf ^ 1])[threadIdx.x + r * 256] = pf[r];
        }
        __syncthreads();
    }

    const float4 as4 = ((const float4*)a_src)[jt];
    const float4 ad4 = ((const float4*)a_dst)[jt];
    const int hh = j4 >> 5;               // head of this thread's 4 columns

#pragma unroll
    for (int m = 0; m < NPT; ++m) {
        int n = node0 + g * NPT + m;
        float4 v = acc[m];
        float sv = v.x * as4.x + v.y * as4.y + v.z * as4.z + v.w * as4.w;
        float dv = v.x * ad4.x + v.y * ad4.y + v.z * ad4.z + v.w * ad4.w;
#pragma unroll
        for (int off = 4; off >= 1; off >>= 1) {   // 8 threads per head
            sv += __shfl_xor(sv, off);
            dv += __shfl_xor(dv, off);
        }
        if (n < N) {
            ushort4 hp;
            hp.x = f2bf(v.x); hp.y = f2bf(v.y);
            hp.z = f2bf(v.z); hp.w = f2bf(v.w);
            ((ushort4*)(hout + (size_t)n * COUT))[jt] = hp;
            if ((jt & 7) == 0) {
                alsrc[n * Hh + hh] = sv;
                aldst[n * Hh + hh] = dv;
            }
        }
    }
}

// ---------------------------------------------------------------------------
// CSR build, bucket-local counting sort (64 dst nodes per bucket).
// ---------------------------------------------------------------------------
#define BKT_CAP 2048    // slots per bucket (E/N*64 ~= 1023 expected)
#define NBKT_MAX 1024   // supports N <= 65536
#define CH_BIN 4096     // edges per bin block

__global__ __launch_bounds__(1024) void bin_kernel(
    const int* __restrict__ src, const int* __restrict__ dst,
    int* __restrict__ bcnt, unsigned int* __restrict__ tmp, int E, int nbkt)
{
    __shared__ int hist[NBKT_MAX];
    __shared__ int base[NBKT_MAX];
    const int e0 = blockIdx.x * CH_BIN;
    const int e1 = min(e0 + CH_BIN, E);

    for (int b = threadIdx.x; b < nbkt; b += 1024) hist[b] = 0;
    __syncthreads();
    for (int e = e0 + threadIdx.x; e < e1; e += 1024) {
        int d = __builtin_nontemporal_load(dst + e);
        atomicAdd(&hist[d >> 6], 1);
    }
    __syncthreads();
    for (int b = threadIdx.x; b < nbkt; b += 1024) {
        int c = hist[b];
        base[b] = (c > 0) ? atomicAdd(&bcnt[b << 4], c) : 0;  // 64B-strided
        hist[b] = 0;                                          // reuse as cursor
    }
    __syncthreads();
    for (int e = e0 + threadIdx.x; e < e1; e += 1024) {
        int d = __builtin_nontemporal_load(dst + e);
        int s = __builtin_nontemporal_load(src + e);
        int b = d >> 6;
        int pos = base[b] + atomicAdd(&hist[b], 1);
        if (pos < BKT_CAP)
            tmp[((size_t)b << 11) + pos] =
                ((unsigned int)s << 6) | (unsigned int)(d & 63);
    }
}

__global__ __launch_bounds__(256) void hist_kernel(
    const unsigned int* __restrict__ tmp, const int* __restrict__ bcnt,
    int* __restrict__ deg, int N)
{
    int b = blockIdx.x;
    __shared__ int hist[64];
    if (threadIdx.x < 64) hist[threadIdx.x] = 0;
    __syncthreads();
    int cnt = min(bcnt[b << 4], BKT_CAP);
    const unsigned int* tb = tmp + ((size_t)b << 11);
    for (int i = threadIdx.x; i < cnt; i += 256)
        atomicAdd(&hist[tb[i] & 63u], 1);
    __syncthreads();
    if (threadIdx.x < 64) {
        int node = (b << 6) + threadIdx.x;
        if (node < N) deg[node] = hist[threadIdx.x];
    }
}

__global__ __launch_bounds__(256) void block_sum_kernel(
    const int* __restrict__ deg, int* __restrict__ blocksums, int N)
{
    int base = blockIdx.x * 4096 + threadIdx.x * 16;
    int s = 0;
#pragma unroll
    for (int i = 0; i < 16; ++i) {
        int idx = base + i;
        if (idx < N) s += deg[idx];
    }
#pragma unroll
    for (int off = 1; off < 64; off <<= 1) s += __shfl_xor(s, off);
    __shared__ int wsum[4];
    if ((threadIdx.x & 63) == 0) wsum[threadIdx.x >> 6] = s;
    __syncthreads();
    if (threadIdx.x == 0)
        blocksums[blockIdx.x] = wsum[0] + wsum[1] + wsum[2] + wsum[3];
}

__global__ __launch_bounds__(64) void scan_sums_kernel(
    const int* __restrict__ blocksums, int* __restrict__ blockbase,
    int* __restrict__ total_out, int nb)
{
    int tid = threadIdx.x;
    int orig = (tid < nb) ? blocksums[tid] : 0;
    int v = orig;
#pragma unroll
    for (int off = 1; off < 64; off <<= 1) {
        int t = __shfl_up(v, off);
        if (tid >= off) v += t;
    }
    if (tid < nb) blockbase[tid] = v - orig;     // exclusive
    if (tid == nb - 1) *total_out = v;           // offsets[N]
}

__global__ __launch_bounds__(256) void scan_final_kernel(
    const int* __restrict__ deg, const int* __restrict__ blockbase,
    int* __restrict__ offsets, int N)
{
    int base = blockIdx.x * 4096 + threadIdx.x * 16;
    int v[16];
    int s = 0;
#pragma unroll
    for (int i = 0; i < 16; ++i) {
        int idx = base + i;
        v[i] = (idx < N) ? deg[idx] : 0;
        s += v[i];
    }
    int lane = threadIdx.x & 63, wid = threadIdx.x >> 6;
    int incl = s;
#pragma unroll
    for (int off = 1; off < 64; off <<= 1) {
        int t = __shfl_up(incl, off);
        if (lane >= off) incl += t;
    }
    __shared__ int wsum[4];
    if (lane == 63) wsum[wid] = incl;
    __syncthreads();
    int woff = 0;
    for (int i = 0; i < wid; ++i) woff += wsum[i];
    int run = blockbase[blockIdx.x] + woff + incl - s;  // thread-exclusive
#pragma unroll
    for (int i = 0; i < 16; ++i) {
        int idx = base + i;
        if (idx < N) offsets[idx] = run;
        run += v[i];
    }
}

__global__ __launch_bounds__(256) void place_kernel(
    const unsigned int* __restrict__ tmp, const int* __restrict__ bcnt,
    const int* __restrict__ offsets, int* __restrict__ src_sorted, int N)
{
    int b = blockIdx.x;
    __shared__ int cur[64];
    if (threadIdx.x < 64) {
        int node = (b << 6) + threadIdx.x;
        cur[threadIdx.x] = (node < N) ? offsets[node] : 0;
    }
    __syncthreads();
    int cnt = min(bcnt[b << 4], BKT_CAP);
    const unsigned int* tb = tmp + ((size_t)b << 11);
    for (int i = threadIdx.x; i < cnt; i += 256) {
        unsigned int p = tb[i];
        int pos = atomicAdd(&cur[p & 63u], 1);
        src_sorted[pos] = (int)(p >> 6);
    }
}

// ---------------------------------------------------------------------------
// Fused GAT aggregation (per-node gather, zero atomics), bf16 h:
// 8 channels per thread (one 16B uint4 load per edge/thread), TPN = HC/8
// threads per node; inner loop unrolled x2 for memory-level parallelism.
// ---------------------------------------------------------------------------
__device__ __forceinline__ void fma8(const uint4& p, float w, float* a) {
    a[0] += w * bflo(p.x); a[1] += w * bfhi(p.x);
    a[2] += w * bflo(p.y); a[3] += w * bfhi(p.y);
    a[4] += w * bflo(p.z); a[5] += w * bfhi(p.z);
    a[6] += w * bflo(p.w); a[7] += w * bfhi(p.w);
}

template <int Hh, int Cc, bool DO_ELU>
__global__ __launch_bounds__(256) void gat_agg_kernel(
    const int* __restrict__ offsets, const int* __restrict__ src_sorted,
    const unsigned short* __restrict__ h, const float* __restrict__ alsrc,
    const float* __restrict__ aldst, const float* __restrict__ bias,
    float* __restrict__ outf, int N)
{
    constexpr int HC  = Hh * Cc;         // 128 or 32
    constexpr int TPN = HC / 8;          // threads per node: 16 or 4
    constexpr int NPB = 256 / TPN;       // nodes per block: 16 or 64
    constexpr int CHUNK = 64;
    __shared__ int   s_src[NPB][CHUNK];
    __shared__ __align__(16) float s_w[NPB][CHUNK][Hh];
    __shared__ int   s_nch[NPB];

    const int g  = threadIdx.x / TPN;
    const int lt = threadIdx.x % TPN;
    const int n  = blockIdx.x * NPB + g;
    const bool valid = n < N;

    int off0 = 0, deg = 0;
    if (valid) { off0 = offsets[n]; deg = offsets[n + 1] - off0; }
    if (lt == 0) s_nch[g] = (deg + CHUNK - 1) / CHUNK;
    __syncthreads();
    int maxch = 0;
#pragma unroll
    for (int i = 0; i < NPB; ++i) maxch = max(maxch, s_nch[i]);

    const int hh = (lt * 8) / Cc;        // head of this thread's 8 channels
    float adv[Hh];
    if (valid) {
        if constexpr (Hh == 4) {
            float4 t = ((const float4*)aldst)[n];
            adv[0] = t.x; adv[1] = t.y; adv[2] = t.z; adv[3] = t.w;
        } else {
            adv[0] = aldst[n];
        }
    }

    const uint4* h4 = (const uint4*)h;   // one row = TPN uint4 (16B = 8 ch)

    float a[8] = {0.f, 0.f, 0.f, 0.f, 0.f, 0.f, 0.f, 0.f};
    float den = 0.f;
    for (int ch = 0; ch < maxch; ++ch) {
        int base = ch * CHUNK;
        int cnt = deg - base;
        cnt = cnt < 0 ? 0 : (cnt > CHUNK ? CHUNK : cnt);
        __syncthreads();                 // LDS reuse fence
        for (int i = lt; i < cnt; i += TPN) {
            int s = src_sorted[off0 + base + i];
            s_src[g][i] = s;
            if constexpr (Hh == 4) {
                float4 av = ((const float4*)alsrc)[s];
                ((float4*)&s_w[g][i][0])[0] = make_float4(
                    __expf(lrelu(av.x + adv[0])), __expf(lrelu(av.y + adv[1])),
                    __expf(lrelu(av.z + adv[2])), __expf(lrelu(av.w + adv[3])));
            } else {
                s_w[g][i][0] = __expf(lrelu(alsrc[s] + adv[0]));
            }
        }
        __syncthreads();
        int i = 0;
        for (; i + 1 < cnt; i += 2) {
            int s0 = s_src[g][i], s1 = s_src[g][i + 1];
            float w0 = s_w[g][i][hh], w1 = s_w[g][i + 1][hh];
            uint4 p0 = h4[(size_t)s0 * TPN + lt];
            uint4 p1 = h4[(size_t)s1 * TPN + lt];
            fma8(p0, w0, a);
            fma8(p1, w1, a);
            den += w0 + w1;
        }
        if (i < cnt) {
            int s0 = s_src[g][i];
            float w0 = s_w[g][i][hh];
            uint4 p0 = h4[(size_t)s0 * TPN + lt];
            fma8(p0, w0, a);
            den += w0;
        }
    }

    if (valid) {
        float wself = __expf(lrelu(alsrc[n * Hh + hh] + adv[hh]));
        uint4 p = h4[(size_t)n * TPN + lt];
        fma8(p, wself, a);
        den += wself + 1e-16f;
        float inv = 1.f / den;
        float4 bv0 = ((const float4*)bias)[lt * 2];
        float4 bv1 = ((const float4*)bias)[lt * 2 + 1];
        float o[8];
        o[0] = a[0] * inv + bv0.x; o[1] = a[1] * inv + bv0.y;
        o[2] = a[2] * inv + bv0.z; o[3] = a[3] * inv + bv0.w;
        o[4] = a[4] * inv + bv1.x; o[5] = a[5] * inv + bv1.y;
        o[6] = a[6] * inv + bv1.z; o[7] = a[7] * inv + bv1.w;
        if (DO_ELU) {
#pragma unroll
            for (int q = 0; q < 8; ++q)
                o[q] = o[q] > 0.f ? o[q] : __expf(o[q]) - 1.f;
        }
        float4* op = (float4*)(outf + (size_t)n * HC);
        op[lt * 2]     = make_float4(o[0], o[1], o[2], o[3]);
        op[lt * 2 + 1] = make_float4(o[4], o[5], o[6], o[7]);
    }
}

// ---------------------------------------------------------------------------
// classification head: out[n,k] = h3[n,:] @ Wc[:,k] + bc[k]   (32 -> 2)
// ---------------------------------------------------------------------------
__global__ __launch_bounds__(256) void head_kernel(
    const float* __restrict__ h3, const float* __restrict__ Wc,
    const float* __restrict__ bc, float* __restrict__ out, int N)
{
    int t = blockIdx.x * 256 + threadIdx.x;
    int n = t / 2, k = t % 2;
    if (n >= N) return;
    float s = bc[k];
#pragma unroll
    for (int c = 0; c < 32; ++c) s += h3[(size_t)n * 32 + c] * Wc[c * 2 + k];
    out[(size_t)n * 2 + k] = s;
}

extern "C" void kernel_launch(void* const* d_in, const int* in_sizes, int n_in,
                              void* d_out, int out_size, void* d_ws, size_t ws_size,
                              hipStream_t stream)
{
    const float* x   = (const float*)d_in[0];
    const int*   ei  = (const int*)d_in[1];
    const float* W1  = (const float*)d_in[2];
    const float* a1s = (const float*)d_in[3];
    const float* a1d = (const float*)d_in[4];
    const float* b1  = (const float*)d_in[5];
    const float* W2  = (const float*)d_in[6];
    const float* a2s = (const float*)d_in[7];
    const float* a2d = (const float*)d_in[8];
    const float* b2  = (const float*)d_in[9];
    const float* W3  = (const float*)d_in[10];
    const float* a3s = (const float*)d_in[11];
    const float* a3d = (const float*)d_in[12];
    const float* b3  = (const float*)d_in[13];
    const float* Wc  = (const float*)d_in[14];
    const float* bc  = (const float*)d_in[15];

    const int N = in_sizes[0] / 128;
    const int E = in_sizes[1] / 2;
    const int* srcIdx = ei;
    const int* dstIdx = ei + E;

    const int NBKT = (N + 63) >> 6;                     // buckets of 64 dsts

    float* ws    = (float*)d_ws;
    float* fbuf  = ws;                                  // N*128 fp32
    float* alsrc = fbuf + (size_t)N * 128;              // N*4 (16B aligned)
    float* aldst = alsrc + (size_t)N * 4;               // N*4
    unsigned short* hbuf = (unsigned short*)(aldst + (size_t)N * 4); // N*128 bf16
    int* deg        = (int*)(hbuf + (size_t)N * 128);   // N
    int* offsets    = deg + N;                          // N+1
    int* src_sorted = offsets + N + 1;                  // E
    int* blocksums  = src_sorted + E;                   // 64
    int* blockbase  = blocksums + 64;                   // 64
    int* bcnt       = blockbase + 64;                   // NBKT*16 (64B-strided)
    unsigned int* tmp = (unsigned int*)(bcnt + (size_t)NBKT * 16); // NBKT*BKT_CAP

    float* node_out = (float*)d_out;                    // N*2
    float* link_out = node_out + (size_t)N * 2;         // N*32

    const int nb = (N + 4095) / 4096;                   // scan blocks (<=64)
    const int nbBin = (E + CH_BIN - 1) / CH_BIN;

    // ---------------- CSR build (dst-sorted), reused by all 3 layers --------
    hipMemsetAsync(bcnt, 0, (size_t)NBKT * 16 * sizeof(int), stream);
    bin_kernel<<<nbBin, 1024, 0, stream>>>(srcIdx, dstIdx, bcnt, tmp, E, NBKT);
    hist_kernel<<<NBKT, 256, 0, stream>>>(tmp, bcnt, deg, N);
    block_sum_kernel<<<nb, 256, 0, stream>>>(deg, blocksums, N);
    scan_sums_kernel<<<1, 64, 0, stream>>>(blocksums, blockbase, offsets + N, nb);
    scan_final_kernel<<<nb, 256, 0, stream>>>(deg, blockbase, offsets, N);
    place_kernel<<<NBKT, 256, 0, stream>>>(tmp, bcnt, offsets, src_sorted, N);

    // ---------------- layer 1 (IN=128 -> H=4,C=32, concat, ELU) -------------
    transform_kernel<128, 4, 4><<<(N + 31) / 32, 256, 0, stream>>>(
        x, W1, a1s, a1d, hbuf, alsrc, aldst, N);
    gat_agg_kernel<4, 32, true><<<(N + 15) / 16, 256, 0, stream>>>(
        offsets, src_sorted, hbuf, alsrc, aldst, b1, fbuf, N);

    // ---------------- layer 2 (128 -> H=4,C=32, concat, ELU) ----------------
    transform_kernel<128, 4, 4><<<(N + 31) / 32, 256, 0, stream>>>(
        fbuf, W2, a2s, a2d, hbuf, alsrc, aldst, N);
    gat_agg_kernel<4, 32, true><<<(N + 15) / 16, 256, 0, stream>>>(
        offsets, src_sorted, hbuf, alsrc, aldst, b2, fbuf, N);

    // ---------------- layer 3 (128 -> H=1,C=32, no concat, no ELU) ----------
    transform_kernel<32, 1, 4><<<(N + 127) / 128, 256, 0, stream>>>(
        fbuf, W3, a3s, a3d, hbuf, alsrc, aldst, N);
    gat_agg_kernel<1, 32, false><<<(N + 63) / 64, 256, 0, stream>>>(
        offsets, src_sorted, hbuf, alsrc, aldst, b3, link_out, N);

    // ---------------- head: node_output = h3 @ Wc + bc ----------------------
    head_kernel<<<(N * 2 + 255) / 256, 256, 0, stream>>>(link_out, Wc, bc, node_out, N);
}

// Round 11
// 322.718 us; speedup vs baseline: 1.1569x; 1.1569x over previous
//
#include <hip/hip_runtime.h>
#include <math.h>

#define SLOPE 0.2f

__device__ __forceinline__ float lrelu(float x) { return x > 0.f ? x : SLOPE * x; }

// bf16 helpers (h is stored bf16 to halve gather traffic; error budget 1e-2)
__device__ __forceinline__ float bflo(unsigned int u) { return __uint_as_float(u << 16); }
__device__ __forceinline__ float bfhi(unsigned int u) { return __uint_as_float(u & 0xffff0000u); }
__device__ __forceinline__ unsigned short f2bf(float f) {   // round-nearest-even
    unsigned int u = __float_as_uint(f);
    unsigned int r = u + 0x7fffu + ((u >> 16) & 1u);
    return (unsigned short)(r >> 16);
}

// ---------------------------------------------------------------------------
// h = x @ W  (CIN=128), fused with attention logits.
// R8 structure (xs in LDS 16.9KB, W per-thread global loads) + distance-1
// REGISTER prefetch of W (R9's LDS double-buffer cost 140 VGPR / 49KB LDS ->
// 9% occupancy, regression; R8's load-then-use chain stalled ~200cy/iter at
// VALUBusy 37%). Prefetch adds ~32 VGPR, no LDS, no barriers.
// ---------------------------------------------------------------------------
template <int COUT, int Hh, int NPT>
__global__ __launch_bounds__(256) void transform_kernel(
    const float* __restrict__ xin, const float* __restrict__ W,
    const float* __restrict__ a_src, const float* __restrict__ a_dst,
    unsigned short* __restrict__ hout, float* __restrict__ alsrc,
    float* __restrict__ aldst, int N)
{
    constexpr int JT = COUT / 4;          // threads per node-group: 32 or 8
    constexpr int GROUPS = 256 / JT;      // node-groups per block: 8 or 32
    constexpr int NB = GROUPS * NPT;      // nodes per block
    constexpr int PAD = 4;
    __shared__ __align__(16) float xs[NB][128 + PAD];

    const int node0 = blockIdx.x * NB;
    const int total4 = NB * 32;           // float4s to stage
    const int lim4 = (N - node0) * 32;
    const float4* src4 = (const float4*)(xin + (size_t)node0 * 128);
    for (int i = threadIdx.x; i < total4; i += 256) {
        int row = i >> 5, col = i & 31;
        float4 v = (i < lim4) ? src4[i] : make_float4(0.f, 0.f, 0.f, 0.f);
        *(float4*)&xs[row][col << 2] = v;
    }
    __syncthreads();

    const int jt = threadIdx.x % JT;      // 4-wide column group
    const int g  = threadIdx.x / JT;
    const int j4 = jt * 4;

    float4 acc[NPT];
#pragma unroll
    for (int m = 0; m < NPT; ++m) acc[m] = make_float4(0.f, 0.f, 0.f, 0.f);

    const float4* Wf4 = (const float4*)W;   // Wf4[k*JT + jt] = W[k][j4..j4+3]
    float4 wc0 = Wf4[0 * JT + jt];
    float4 wc1 = Wf4[1 * JT + jt];
    float4 wc2 = Wf4[2 * JT + jt];
    float4 wc3 = Wf4[3 * JT + jt];

    for (int k4 = 0; k4 < 32; ++k4) {
        // prefetch next k4's W rows (redundant reload of row 31 on last iter)
        const int kn = (k4 < 31 ? k4 + 1 : 31) * 4;
        float4 wn0 = Wf4[(kn + 0) * JT + jt];
        float4 wn1 = Wf4[(kn + 1) * JT + jt];
        float4 wn2 = Wf4[(kn + 2) * JT + jt];
        float4 wn3 = Wf4[(kn + 3) * JT + jt];
#pragma unroll
        for (int m = 0; m < NPT; ++m) {
            float4 xv = *(const float4*)&xs[g * NPT + m][k4 << 2];
            acc[m].x += xv.x * wc0.x + xv.y * wc1.x + xv.z * wc2.x + xv.w * wc3.x;
            acc[m].y += xv.x * wc0.y + xv.y * wc1.y + xv.z * wc2.y + xv.w * wc3.y;
            acc[m].z += xv.x * wc0.z + xv.y * wc1.z + xv.z * wc2.z + xv.w * wc3.z;
            acc[m].w += xv.x * wc0.w + xv.y * wc1.w + xv.z * wc2.w + xv.w * wc3.w;
        }
        wc0 = wn0; wc1 = wn1; wc2 = wn2; wc3 = wn3;
    }

    const float4 as4 = ((const float4*)a_src)[jt];
    const float4 ad4 = ((const float4*)a_dst)[jt];
    const int hh = j4 >> 5;               // head of this thread's 4 columns

#pragma unroll
    for (int m = 0; m < NPT; ++m) {
        int n = node0 + g * NPT + m;
        float4 v = acc[m];
        float sv = v.x * as4.x + v.y * as4.y + v.z * as4.z + v.w * as4.w;
        float dv = v.x * ad4.x + v.y * ad4.y + v.z * ad4.z + v.w * ad4.w;
#pragma unroll
        for (int off = 4; off >= 1; off >>= 1) {   // 8 threads per head
            sv += __shfl_xor(sv, off);
            dv += __shfl_xor(dv, off);
        }
        if (n < N) {
            ushort4 hp;
            hp.x = f2bf(v.x); hp.y = f2bf(v.y);
            hp.z = f2bf(v.z); hp.w = f2bf(v.w);
            ((ushort4*)(hout + (size_t)n * COUT))[jt] = hp;
            if ((jt & 7) == 0) {
                alsrc[n * Hh + hh] = sv;
                aldst[n * Hh + hh] = dv;
            }
        }
    }
}

// ---------------------------------------------------------------------------
// CSR build, bucket-local counting sort (64 dst nodes per bucket).
// ---------------------------------------------------------------------------
#define BKT_CAP 2048    // slots per bucket (E/N*64 ~= 1023 expected)
#define NBKT_MAX 1024   // supports N <= 65536
#define CH_BIN 4096     // edges per bin block

__global__ __launch_bounds__(1024) void bin_kernel(
    const int* __restrict__ src, const int* __restrict__ dst,
    int* __restrict__ bcnt, unsigned int* __restrict__ tmp, int E, int nbkt)
{
    __shared__ int hist[NBKT_MAX];
    __shared__ int base[NBKT_MAX];
    const int e0 = blockIdx.x * CH_BIN;
    const int e1 = min(e0 + CH_BIN, E);

    for (int b = threadIdx.x; b < nbkt; b += 1024) hist[b] = 0;
    __syncthreads();
    for (int e = e0 + threadIdx.x; e < e1; e += 1024) {
        int d = __builtin_nontemporal_load(dst + e);
        atomicAdd(&hist[d >> 6], 1);
    }
    __syncthreads();
    for (int b = threadIdx.x; b < nbkt; b += 1024) {
        int c = hist[b];
        base[b] = (c > 0) ? atomicAdd(&bcnt[b << 4], c) : 0;  // 64B-strided
        hist[b] = 0;                                          // reuse as cursor
    }
    __syncthreads();
    for (int e = e0 + threadIdx.x; e < e1; e += 1024) {
        int d = __builtin_nontemporal_load(dst + e);
        int s = __builtin_nontemporal_load(src + e);
        int b = d >> 6;
        int pos = base[b] + atomicAdd(&hist[b], 1);
        if (pos < BKT_CAP)
            tmp[((size_t)b << 11) + pos] =
                ((unsigned int)s << 6) | (unsigned int)(d & 63);
    }
}

__global__ __launch_bounds__(256) void hist_kernel(
    const unsigned int* __restrict__ tmp, const int* __restrict__ bcnt,
    int* __restrict__ deg, int N)
{
    int b = blockIdx.x;
    __shared__ int hist[64];
    if (threadIdx.x < 64) hist[threadIdx.x] = 0;
    __syncthreads();
    int cnt = min(bcnt[b << 4], BKT_CAP);
    const unsigned int* tb = tmp + ((size_t)b << 11);
    for (int i = threadIdx.x; i < cnt; i += 256)
        atomicAdd(&hist[tb[i] & 63u], 1);
    __syncthreads();
    if (threadIdx.x < 64) {
        int node = (b << 6) + threadIdx.x;
        if (node < N) deg[node] = hist[threadIdx.x];
    }
}

__global__ __launch_bounds__(256) void block_sum_kernel(
    const int* __restrict__ deg, int* __restrict__ blocksums, int N)
{
    int base = blockIdx.x * 4096 + threadIdx.x * 16;
    int s = 0;
#pragma unroll
    for (int i = 0; i < 16; ++i) {
        int idx = base + i;
        if (idx < N) s += deg[idx];
    }
#pragma unroll
    for (int off = 1; off < 64; off <<= 1) s += __shfl_xor(s, off);
    __shared__ int wsum[4];
    if ((threadIdx.x & 63) == 0) wsum[threadIdx.x >> 6] = s;
    __syncthreads();
    if (threadIdx.x == 0)
        blocksums[blockIdx.x] = wsum[0] + wsum[1] + wsum[2] + wsum[3];
}

__global__ __launch_bounds__(64) void scan_sums_kernel(
    const int* __restrict__ blocksums, int* __restrict__ blockbase,
    int* __restrict__ total_out, int nb)
{
    int tid = threadIdx.x;
    int orig = (tid < nb) ? blocksums[tid] : 0;
    int v = orig;
#pragma unroll
    for (int off = 1; off < 64; off <<= 1) {
        int t = __shfl_up(v, off);
        if (tid >= off) v += t;
    }
    if (tid < nb) blockbase[tid] = v - orig;     // exclusive
    if (tid == nb - 1) *total_out = v;           // offsets[N]
}

__global__ __launch_bounds__(256) void scan_final_kernel(
    const int* __restrict__ deg, const int* __restrict__ blockbase,
    int* __restrict__ offsets, int N)
{
    int base = blockIdx.x * 4096 + threadIdx.x * 16;
    int v[16];
    int s = 0;
#pragma unroll
    for (int i = 0; i < 16; ++i) {
        int idx = base + i;
        v[i] = (idx < N) ? deg[idx] : 0;
        s += v[i];
    }
    int lane = threadIdx.x & 63, wid = threadIdx.x >> 6;
    int incl = s;
#pragma unroll
    for (int off = 1; off < 64; off <<= 1) {
        int t = __shfl_up(incl, off);
        if (lane >= off) incl += t;
    }
    __shared__ int wsum[4];
    if (lane == 63) wsum[wid] = incl;
    __syncthreads();
    int woff = 0;
    for (int i = 0; i < wid; ++i) woff += wsum[i];
    int run = blockbase[blockIdx.x] + woff + incl - s;  // thread-exclusive
#pragma unroll
    for (int i = 0; i < 16; ++i) {
        int idx = base + i;
        if (idx < N) offsets[idx] = run;
        run += v[i];
    }
}

__global__ __launch_bounds__(256) void place_kernel(
    const unsigned int* __restrict__ tmp, const int* __restrict__ bcnt,
    const int* __restrict__ offsets, int* __restrict__ src_sorted, int N)
{
    int b = blockIdx.x;
    __shared__ int cur[64];
    if (threadIdx.x < 64) {
        int node = (b << 6) + threadIdx.x;
        cur[threadIdx.x] = (node < N) ? offsets[node] : 0;
    }
    __syncthreads();
    int cnt = min(bcnt[b << 4], BKT_CAP);
    const unsigned int* tb = tmp + ((size_t)b << 11);
    for (int i = threadIdx.x; i < cnt; i += 256) {
        unsigned int p = tb[i];
        int pos = atomicAdd(&cur[p & 63u], 1);
        src_sorted[pos] = (int)(p >> 6);
    }
}

// ---------------------------------------------------------------------------
// Fused GAT aggregation (per-node gather, zero atomics), bf16 h:
// 8 channels per thread (one 16B uint4 load per edge/thread), TPN = HC/8
// threads per node; inner loop unrolled x2 for memory-level parallelism.
// ---------------------------------------------------------------------------
__device__ __forceinline__ void fma8(const uint4& p, float w, float* a) {
    a[0] += w * bflo(p.x); a[1] += w * bfhi(p.x);
    a[2] += w * bflo(p.y); a[3] += w * bfhi(p.y);
    a[4] += w * bflo(p.z); a[5] += w * bfhi(p.z);
    a[6] += w * bflo(p.w); a[7] += w * bfhi(p.w);
}

template <int Hh, int Cc, bool DO_ELU>
__global__ __launch_bounds__(256) void gat_agg_kernel(
    const int* __restrict__ offsets, const int* __restrict__ src_sorted,
    const unsigned short* __restrict__ h, const float* __restrict__ alsrc,
    const float* __restrict__ aldst, const float* __restrict__ bias,
    float* __restrict__ outf, int N)
{
    constexpr int HC  = Hh * Cc;         // 128 or 32
    constexpr int TPN = HC / 8;          // threads per node: 16 or 4
    constexpr int NPB = 256 / TPN;       // nodes per block: 16 or 64
    constexpr int CHUNK = 64;
    __shared__ int   s_src[NPB][CHUNK];
    __shared__ __align__(16) float s_w[NPB][CHUNK][Hh];
    __shared__ int   s_nch[NPB];

    const int g  = threadIdx.x / TPN;
    const int lt = threadIdx.x % TPN;
    const int n  = blockIdx.x * NPB + g;
    const bool valid = n < N;

    int off0 = 0, deg = 0;
    if (valid) { off0 = offsets[n]; deg = offsets[n + 1] - off0; }
    if (lt == 0) s_nch[g] = (deg + CHUNK - 1) / CHUNK;
    __syncthreads();
    int maxch = 0;
#pragma unroll
    for (int i = 0; i < NPB; ++i) maxch = max(maxch, s_nch[i]);

    const int hh = (lt * 8) / Cc;        // head of this thread's 8 channels
    float adv[Hh];
    if (valid) {
        if constexpr (Hh == 4) {
            float4 t = ((const float4*)aldst)[n];
            adv[0] = t.x; adv[1] = t.y; adv[2] = t.z; adv[3] = t.w;
        } else {
            adv[0] = aldst[n];
        }
    }

    const uint4* h4 = (const uint4*)h;   // one row = TPN uint4 (16B = 8 ch)

    float a[8] = {0.f, 0.f, 0.f, 0.f, 0.f, 0.f, 0.f, 0.f};
    float den = 0.f;
    for (int ch = 0; ch < maxch; ++ch) {
        int base = ch * CHUNK;
        int cnt = deg - base;
        cnt = cnt < 0 ? 0 : (cnt > CHUNK ? CHUNK : cnt);
        __syncthreads();                 // LDS reuse fence
        for (int i = lt; i < cnt; i += TPN) {
            int s = src_sorted[off0 + base + i];
            s_src[g][i] = s;
            if constexpr (Hh == 4) {
                float4 av = ((const float4*)alsrc)[s];
                ((float4*)&s_w[g][i][0])[0] = make_float4(
                    __expf(lrelu(av.x + adv[0])), __expf(lrelu(av.y + adv[1])),
                    __expf(lrelu(av.z + adv[2])), __expf(lrelu(av.w + adv[3])));
            } else {
                s_w[g][i][0] = __expf(lrelu(alsrc[s] + adv[0]));
            }
        }
        __syncthreads();
        int i = 0;
        for (; i + 1 < cnt; i += 2) {
            int s0 = s_src[g][i], s1 = s_src[g][i + 1];
            float w0 = s_w[g][i][hh], w1 = s_w[g][i + 1][hh];
            uint4 p0 = h4[(size_t)s0 * TPN + lt];
            uint4 p1 = h4[(size_t)s1 * TPN + lt];
            fma8(p0, w0, a);
            fma8(p1, w1, a);
            den += w0 + w1;
        }
        if (i < cnt) {
            int s0 = s_src[g][i];
            float w0 = s_w[g][i][hh];
            uint4 p0 = h4[(size_t)s0 * TPN + lt];
            fma8(p0, w0, a);
            den += w0;
        }
    }

    if (valid) {
        float wself = __expf(lrelu(alsrc[n * Hh + hh] + adv[hh]));
        uint4 p = h4[(size_t)n * TPN + lt];
        fma8(p, wself, a);
        den += wself + 1e-16f;
        float inv = 1.f / den;
        float4 bv0 = ((const float4*)bias)[lt * 2];
        float4 bv1 = ((const float4*)bias)[lt * 2 + 1];
        float o[8];
        o[0] = a[0] * inv + bv0.x; o[1] = a[1] * inv + bv0.y;
        o[2] = a[2] * inv + bv0.z; o[3] = a[3] * inv + bv0.w;
        o[4] = a[4] * inv + bv1.x; o[5] = a[5] * inv + bv1.y;
        o[6] = a[6] * inv + bv1.z; o[7] = a[7] * inv + bv1.w;
        if (DO_ELU) {
#pragma unroll
            for (int q = 0; q < 8; ++q)
                o[q] = o[q] > 0.f ? o[q] : __expf(o[q]) - 1.f;
        }
        float4* op = (float4*)(outf + (size_t)n * HC);
        op[lt * 2]     = make_float4(o[0], o[1], o[2], o[3]);
        op[lt * 2 + 1] = make_float4(o[4], o[5], o[6], o[7]);
    }
}

// ---------------------------------------------------------------------------
// classification head: out[n,k] = h3[n,:] @ Wc[:,k] + bc[k]   (32 -> 2)
// ---------------------------------------------------------------------------
__global__ __launch_bounds__(256) void head_kernel(
    const float* __restrict__ h3, const float* __restrict__ Wc,
    const float* __restrict__ bc, float* __restrict__ out, int N)
{
    int t = blockIdx.x * 256 + threadIdx.x;
    int n = t / 2, k = t % 2;
    if (n >= N) return;
    float s = bc[k];
#pragma unroll
    for (int c = 0; c < 32; ++c) s += h3[(size_t)n * 32 + c] * Wc[c * 2 + k];
    out[(size_t)n * 2 + k] = s;
}

extern "C" void kernel_launch(void* const* d_in, const int* in_sizes, int n_in,
                              void* d_out, int out_size, void* d_ws, size_t ws_size,
                              hipStream_t stream)
{
    const float* x   = (const float*)d_in[0];
    const int*   ei  = (const int*)d_in[1];
    const float* W1  = (const float*)d_in[2];
    const float* a1s = (const float*)d_in[3];
    const float* a1d = (const float*)d_in[4];
    const float* b1  = (const float*)d_in[5];
    const float* W2  = (const float*)d_in[6];
    const float* a2s = (const float*)d_in[7];
    const float* a2d = (const float*)d_in[8];
    const float* b2  = (const float*)d_in[9];
    const float* W3  = (const float*)d_in[10];
    const float* a3s = (const float*)d_in[11];
    const float* a3d = (const float*)d_in[12];
    const float* b3  = (const float*)d_in[13];
    const float* Wc  = (const float*)d_in[14];
    const float* bc  = (const float*)d_in[15];

    const int N = in_sizes[0] / 128;
    const int E = in_sizes[1] / 2;
    const int* srcIdx = ei;
    const int* dstIdx = ei + E;

    const int NBKT = (N + 63) >> 6;                     // buckets of 64 dsts

    float* ws    = (float*)d_ws;
    float* fbuf  = ws;                                  // N*128 fp32
    float* alsrc = fbuf + (size_t)N * 128;              // N*4 (16B aligned)
    float* aldst = alsrc + (size_t)N * 4;               // N*4
    unsigned short* hbuf = (unsigned short*)(aldst + (size_t)N * 4); // N*128 bf16
    int* deg        = (int*)(hbuf + (size_t)N * 128);   // N
    int* offsets    = deg + N;                          // N+1
    int* src_sorted = offsets + N + 1;                  // E
    int* blocksums  = src_sorted + E;                   // 64
    int* blockbase  = blocksums + 64;                   // 64
    int* bcnt       = blockbase + 64;                   // NBKT*16 (64B-strided)
    unsigned int* tmp = (unsigned int*)(bcnt + (size_t)NBKT * 16); // NBKT*BKT_CAP

    float* node_out = (float*)d_out;                    // N*2
    float* link_out = node_out + (size_t)N * 2;         // N*32

    const int nb = (N + 4095) / 4096;                   // scan blocks (<=64)
    const int nbBin = (E + CH_BIN - 1) / CH_BIN;

    // ---------------- CSR build (dst-sorted), reused by all 3 layers --------
    hipMemsetAsync(bcnt, 0, (size_t)NBKT * 16 * sizeof(int), stream);
    bin_kernel<<<nbBin, 1024, 0, stream>>>(srcIdx, dstIdx, bcnt, tmp, E, NBKT);
    hist_kernel<<<NBKT, 256, 0, stream>>>(tmp, bcnt, deg, N);
    block_sum_kernel<<<nb, 256, 0, stream>>>(deg, blocksums, N);
    scan_sums_kernel<<<1, 64, 0, stream>>>(blocksums, blockbase, offsets + N, nb);
    scan_final_kernel<<<nb, 256, 0, stream>>>(deg, blockbase, offsets, N);
    place_kernel<<<NBKT, 256, 0, stream>>>(tmp, bcnt, offsets, src_sorted, N);

    // ---------------- layer 1 (IN=128 -> H=4,C=32, concat, ELU) -------------
    transform_kernel<128, 4, 4><<<(N + 31) / 32, 256, 0, stream>>>(
        x, W1, a1s, a1d, hbuf, alsrc, aldst, N);
    gat_agg_kernel<4, 32, true><<<(N + 15) / 16, 256, 0, stream>>>(
        offsets, src_sorted, hbuf, alsrc, aldst, b1, fbuf, N);

    // ---------------- layer 2 (128 -> H=4,C=32, concat, ELU) ----------------
    transform_kernel<128, 4, 4><<<(N + 31) / 32, 256, 0, stream>>>(
        fbuf, W2, a2s, a2d, hbuf, alsrc, aldst, N);
    gat_agg_kernel<4, 32, true><<<(N + 15) / 16, 256, 0, stream>>>(
        offsets, src_sorted, hbuf, alsrc, aldst, b2, fbuf, N);

    // ---------------- layer 3 (128 -> H=1,C=32, no concat, no ELU) ----------
    transform_kernel<32, 1, 4><<<(N + 127) / 128, 256, 0, stream>>>(
        fbuf, W3, a3s, a3d, hbuf, alsrc, aldst, N);
    gat_agg_kernel<1, 32, false><<<(N + 63) / 64, 256, 0, stream>>>(
        offsets, src_sorted, hbuf, alsrc, aldst, b3, link_out, N);

    // ---------------- head: node_output = h3 @ Wc + bc ----------------------
    head_kernel<<<(N * 2 + 255) / 256, 256, 0, stream>>>(link_out, Wc, bc, node_out, N);
}

// Round 13
// 295.499 us; speedup vs baseline: 1.2635x; 1.0921x over previous
//
#include <hip/hip_runtime.h>
#include <math.h>

#define SLOPE 0.2f

__device__ __forceinline__ float lrelu(float x) { return x > 0.f ? x : SLOPE * x; }

// bf16 helpers (h is stored bf16 to halve gather traffic; error budget 1e-2)
__device__ __forceinline__ float bflo(unsigned int u) { return __uint_as_float(u << 16); }
__device__ __forceinline__ float bfhi(unsigned int u) { return __uint_as_float(u & 0xffff0000u); }
__device__ __forceinline__ unsigned short f2bf(float f) {   // round-nearest-even
    unsigned int u = __float_as_uint(f);
    unsigned int r = u + 0x7fffu + ((u >> 16) & 1u);
    return (unsigned short)(r >> 16);
}

typedef short frag8 __attribute__((ext_vector_type(8)));   // 8 bf16 (4 VGPR)
typedef float f32x4 __attribute__((ext_vector_type(4)));   // MFMA acc

// ---------------------------------------------------------------------------
// One-off: Wt[n][k] = bf16(W[k][n]) for W1 and W2 (128x128 each).
// ---------------------------------------------------------------------------
__global__ __launch_bounds__(256) void wtrans_kernel(
    const float* __restrict__ W1, const float* __restrict__ W2,
    unsigned short* __restrict__ Wt1, unsigned short* __restrict__ Wt2)
{
    int idx = blockIdx.x * 256 + threadIdx.x;   // grid 128 -> 32768
    const float* W = W1;
    unsigned short* Wt = Wt1;
    int i = idx;
    if (idx >= 16384) { W = W2; Wt = Wt2; i = idx - 16384; }
    int n = i >> 7, k = i & 127;
    Wt[i] = f2bf(W[k * 128 + n]);
}

// ---------------------------------------------------------------------------
// MFMA transform for layers 1-2 (CIN=128 -> COUT=128, H=4):
//   h = bf16(x) @ bf16(W), fp32 accumulate via mfma_f32_16x16x32_bf16.
// Block: 64 nodes x 128 cols, 4 waves; wave w owns cols [32w,32w+32)
// (= head w), all 64 rows -> 8 acc tiles (4 Mtiles x 2 Ntiles).
// A[m=lane&15][k=(lane>>4)*8+j], B[k=(lane>>4)*8+j][n=lane&15],
// D[m=(lane>>4)*4+reg][n=lane&15].
// Logits from fp32 accumulators via shfl reduction over the 16 n-lanes.
// h written back bf16 via LDS transpose (coalesced 16B stores).
// R12 fixes: (a) h-store mapping was row=t>>1 (covered 128 rows / half cols;
// OOB + poison) -> row=t>>2, cbase=(t&3)*32; (b) Wt buffer 16B-aligned
// (was 4B -> misaligned uint4 loads -> garbage -> inf -> NaN).
// ---------------------------------------------------------------------------
__global__ __launch_bounds__(256) void transform_mfma_kernel(
    const float* __restrict__ xin, const unsigned short* __restrict__ Wt,
    const float* __restrict__ a_src, const float* __restrict__ a_dst,
    unsigned short* __restrict__ hout, float* __restrict__ alsrc,
    float* __restrict__ aldst, int N)
{
    constexpr int MB = 64;               // nodes per block
    constexpr int LDK = 136;             // padded row (bf16): +16B breaks conflicts
    __shared__ __align__(16) unsigned short xs[MB * LDK];    // x tile / h tile
    __shared__ __align__(16) unsigned short wt[128 * LDK];   // Wt[n][k]

    const int node0 = blockIdx.x * MB;
    const int t = threadIdx.x;

    // stage x (fp32 -> bf16), zero-pad tail rows
    for (int i = t; i < MB * 32; i += 256) {
        int row = i >> 5, col4 = i & 31;
        ushort4 o;
        if (node0 + row < N) {
            float4 v = ((const float4*)(xin + (size_t)(node0 + row) * 128))[col4];
            o.x = f2bf(v.x); o.y = f2bf(v.y); o.z = f2bf(v.z); o.w = f2bf(v.w);
        } else {
            o.x = o.y = o.z = o.w = 0;
        }
        *(ushort4*)&xs[row * LDK + col4 * 4] = o;
    }
    // stage Wt (bf16, already [n][k]) with pad insertion
    for (int i = t; i < 2048; i += 256) {            // 2048 x 16B = 32KB
        int n = i >> 4, k16 = i & 15;
        uint4 v = ((const uint4*)Wt)[i];
        *(uint4*)&wt[n * LDK + k16 * 8] = v;
    }
    __syncthreads();

    const int w    = t >> 6;             // wave = head
    const int lane = t & 63;
    const int r    = lane & 15;
    const int q    = lane >> 4;

    f32x4 acc[4][2];
#pragma unroll
    for (int mt = 0; mt < 4; ++mt)
#pragma unroll
        for (int nl = 0; nl < 2; ++nl)
            acc[mt][nl] = (f32x4){0.f, 0.f, 0.f, 0.f};

#pragma unroll
    for (int kk = 0; kk < 4; ++kk) {
        const int kof = kk * 32 + q * 8;
        frag8 b0 = *(const frag8*)&wt[(w * 32 + r) * LDK + kof];
        frag8 b1 = *(const frag8*)&wt[(w * 32 + 16 + r) * LDK + kof];
#pragma unroll
        for (int mt = 0; mt < 4; ++mt) {
            frag8 a = *(const frag8*)&xs[(mt * 16 + r) * LDK + kof];
            acc[mt][0] = __builtin_amdgcn_mfma_f32_16x16x32_bf16(a, b0, acc[mt][0], 0, 0, 0);
            acc[mt][1] = __builtin_amdgcn_mfma_f32_16x16x32_bf16(a, b1, acc[mt][1], 0, 0, 0);
        }
    }

    // ---- logits from fp32 acc: al[m][w] = sum_n D[m][n]*a[w][n] ----
    const float as0 = a_src[w * 32 + r],      ad0 = a_dst[w * 32 + r];
    const float as1 = a_src[w * 32 + 16 + r], ad1 = a_dst[w * 32 + 16 + r];
#pragma unroll
    for (int mt = 0; mt < 4; ++mt) {
#pragma unroll
        for (int reg = 0; reg < 4; ++reg) {
            float s = acc[mt][0][reg] * as0 + acc[mt][1][reg] * as1;
            float d = acc[mt][0][reg] * ad0 + acc[mt][1][reg] * ad1;
#pragma unroll
            for (int off = 1; off < 16; off <<= 1) {
                s += __shfl_xor(s, off);
                d += __shfl_xor(d, off);
            }
            if (r == 0) {
                int m = mt * 16 + q * 4 + reg;
                int n = node0 + m;
                if (n < N) {
                    alsrc[n * 4 + w] = s;
                    aldst[n * 4 + w] = d;
                }
            }
        }
    }

    // ---- h -> LDS (bf16, D-layout scatter), then coalesced global store ----
    __syncthreads();                     // all waves done reading xs
#pragma unroll
    for (int mt = 0; mt < 4; ++mt)
#pragma unroll
        for (int nl = 0; nl < 2; ++nl)
#pragma unroll
            for (int reg = 0; reg < 4; ++reg) {
                int m = mt * 16 + q * 4 + reg;
                int n = w * 32 + nl * 16 + r;
                xs[m * LDK + n] = f2bf(acc[mt][nl][reg]);
            }
    __syncthreads();
    {
        int row = t >> 2, cbase = (t & 3) * 32;      // 4 threads/row, 32 bf16 each
        if (node0 + row < N) {
            uint4* dst = (uint4*)(hout + (size_t)(node0 + row) * 128 + cbase);
#pragma unroll
            for (int j = 0; j < 4; ++j)
                dst[j] = *(const uint4*)&xs[row * LDK + cbase + j * 8];
        }
    }
}

// ---------------------------------------------------------------------------
// VALU transform for layer 3 (CIN=128 -> COUT=32, H=1), fused logits.
// ---------------------------------------------------------------------------
template <int COUT, int Hh, int NPT>
__global__ __launch_bounds__(256) void transform_kernel(
    const float* __restrict__ xin, const float* __restrict__ W,
    const float* __restrict__ a_src, const float* __restrict__ a_dst,
    unsigned short* __restrict__ hout, float* __restrict__ alsrc,
    float* __restrict__ aldst, int N)
{
    constexpr int JT = COUT / 4;
    constexpr int GROUPS = 256 / JT;
    constexpr int NB = GROUPS * NPT;
    constexpr int PAD = 4;
    __shared__ __align__(16) float xs[NB][128 + PAD];

    const int node0 = blockIdx.x * NB;
    const int total4 = NB * 32;
    const int lim4 = (N - node0) * 32;
    const float4* src4 = (const float4*)(xin + (size_t)node0 * 128);
    for (int i = threadIdx.x; i < total4; i += 256) {
        int row = i >> 5, col = i & 31;
        float4 v = (i < lim4) ? src4[i] : make_float4(0.f, 0.f, 0.f, 0.f);
        *(float4*)&xs[row][col << 2] = v;
    }
    __syncthreads();

    const int jt = threadIdx.x % JT;
    const int g  = threadIdx.x / JT;
    const int j4 = jt * 4;

    float4 acc[NPT];
#pragma unroll
    for (int m = 0; m < NPT; ++m) acc[m] = make_float4(0.f, 0.f, 0.f, 0.f);

    const float4* Wf4 = (const float4*)W;
    for (int k4 = 0; k4 < 32; ++k4) {
        float4 w0 = Wf4[(4 * k4 + 0) * JT + jt];
        float4 w1 = Wf4[(4 * k4 + 1) * JT + jt];
        float4 w2 = Wf4[(4 * k4 + 2) * JT + jt];
        float4 w3 = Wf4[(4 * k4 + 3) * JT + jt];
#pragma unroll
        for (int m = 0; m < NPT; ++m) {
            float4 xv = *(const float4*)&xs[g * NPT + m][k4 << 2];
            acc[m].x += xv.x * w0.x + xv.y * w1.x + xv.z * w2.x + xv.w * w3.x;
            acc[m].y += xv.x * w0.y + xv.y * w1.y + xv.z * w2.y + xv.w * w3.y;
            acc[m].z += xv.x * w0.z + xv.y * w1.z + xv.z * w2.z + xv.w * w3.z;
            acc[m].w += xv.x * w0.w + xv.y * w1.w + xv.z * w2.w + xv.w * w3.w;
        }
    }

    const float4 as4 = ((const float4*)a_src)[jt];
    const float4 ad4 = ((const float4*)a_dst)[jt];
    const int hh = j4 >> 5;

#pragma unroll
    for (int m = 0; m < NPT; ++m) {
        int n = node0 + g * NPT + m;
        float4 v = acc[m];
        float sv = v.x * as4.x + v.y * as4.y + v.z * as4.z + v.w * as4.w;
        float dv = v.x * ad4.x + v.y * ad4.y + v.z * ad4.z + v.w * ad4.w;
#pragma unroll
        for (int off = 4; off >= 1; off >>= 1) {
            sv += __shfl_xor(sv, off);
            dv += __shfl_xor(dv, off);
        }
        if (n < N) {
            ushort4 hp;
            hp.x = f2bf(v.x); hp.y = f2bf(v.y);
            hp.z = f2bf(v.z); hp.w = f2bf(v.w);
            ((ushort4*)(hout + (size_t)n * COUT))[jt] = hp;
            if ((jt & 7) == 0) {
                alsrc[n * Hh + hh] = sv;
                aldst[n * Hh + hh] = dv;
            }
        }
    }
}

// ---------------------------------------------------------------------------
// CSR build, bucket-local counting sort (64 dst nodes per bucket).
// ---------------------------------------------------------------------------
#define BKT_CAP 2048
#define NBKT_MAX 1024
#define CH_BIN 4096

__global__ __launch_bounds__(1024) void bin_kernel(
    const int* __restrict__ src, const int* __restrict__ dst,
    int* __restrict__ bcnt, unsigned int* __restrict__ tmp, int E, int nbkt)
{
    __shared__ int hist[NBKT_MAX];
    __shared__ int base[NBKT_MAX];
    const int e0 = blockIdx.x * CH_BIN;
    const int e1 = min(e0 + CH_BIN, E);

    for (int b = threadIdx.x; b < nbkt; b += 1024) hist[b] = 0;
    __syncthreads();
    for (int e = e0 + threadIdx.x; e < e1; e += 1024) {
        int d = __builtin_nontemporal_load(dst + e);
        atomicAdd(&hist[d >> 6], 1);
    }
    __syncthreads();
    for (int b = threadIdx.x; b < nbkt; b += 1024) {
        int c = hist[b];
        base[b] = (c > 0) ? atomicAdd(&bcnt[b << 4], c) : 0;  // 64B-strided
        hist[b] = 0;
    }
    __syncthreads();
    for (int e = e0 + threadIdx.x; e < e1; e += 1024) {
        int d = __builtin_nontemporal_load(dst + e);
        int s = __builtin_nontemporal_load(src + e);
        int b = d >> 6;
        int pos = base[b] + atomicAdd(&hist[b], 1);
        if (pos < BKT_CAP)
            tmp[((size_t)b << 11) + pos] =
                ((unsigned int)s << 6) | (unsigned int)(d & 63);
    }
}

__global__ __launch_bounds__(256) void hist_kernel(
    const unsigned int* __restrict__ tmp, const int* __restrict__ bcnt,
    int* __restrict__ deg, int N)
{
    int b = blockIdx.x;
    __shared__ int hist[64];
    if (threadIdx.x < 64) hist[threadIdx.x] = 0;
    __syncthreads();
    int cnt = min(bcnt[b << 4], BKT_CAP);
    const unsigned int* tb = tmp + ((size_t)b << 11);
    for (int i = threadIdx.x; i < cnt; i += 256)
        atomicAdd(&hist[tb[i] & 63u], 1);
    __syncthreads();
    if (threadIdx.x < 64) {
        int node = (b << 6) + threadIdx.x;
        if (node < N) deg[node] = hist[threadIdx.x];
    }
}

__global__ __launch_bounds__(256) void block_sum_kernel(
    const int* __restrict__ deg, int* __restrict__ blocksums, int N)
{
    int base = blockIdx.x * 4096 + threadIdx.x * 16;
    int s = 0;
#pragma unroll
    for (int i = 0; i < 16; ++i) {
        int idx = base + i;
        if (idx < N) s += deg[idx];
    }
#pragma unroll
    for (int off = 1; off < 64; off <<= 1) s += __shfl_xor(s, off);
    __shared__ int wsum[4];
    if ((threadIdx.x & 63) == 0) wsum[threadIdx.x >> 6] = s;
    __syncthreads();
    if (threadIdx.x == 0)
        blocksums[blockIdx.x] = wsum[0] + wsum[1] + wsum[2] + wsum[3];
}

__global__ __launch_bounds__(64) void scan_sums_kernel(
    const int* __restrict__ blocksums, int* __restrict__ blockbase,
    int* __restrict__ total_out, int nb)
{
    int tid = threadIdx.x;
    int orig = (tid < nb) ? blocksums[tid] : 0;
    int v = orig;
#pragma unroll
    for (int off = 1; off < 64; off <<= 1) {
        int t = __shfl_up(v, off);
        if (tid >= off) v += t;
    }
    if (tid < nb) blockbase[tid] = v - orig;
    if (tid == nb - 1) *total_out = v;
}

__global__ __launch_bounds__(256) void scan_final_kernel(
    const int* __restrict__ deg, const int* __restrict__ blockbase,
    int* __restrict__ offsets, int N)
{
    int base = blockIdx.x * 4096 + threadIdx.x * 16;
    int v[16];
    int s = 0;
#pragma unroll
    for (int i = 0; i < 16; ++i) {
        int idx = base + i;
        v[i] = (idx < N) ? deg[idx] : 0;
        s += v[i];
    }
    int lane = threadIdx.x & 63, wid = threadIdx.x >> 6;
    int incl = s;
#pragma unroll
    for (int off = 1; off < 64; off <<= 1) {
        int t = __shfl_up(incl, off);
        if (lane >= off) incl += t;
    }
    __shared__ int wsum[4];
    if (lane == 63) wsum[wid] = incl;
    __syncthreads();
    int woff = 0;
    for (int i = 0; i < wid; ++i) woff += wsum[i];
    int run = blockbase[blockIdx.x] + woff + incl - s;
#pragma unroll
    for (int i = 0; i < 16; ++i) {
        int idx = base + i;
        if (idx < N) offsets[idx] = run;
        run += v[i];
    }
}

__global__ __launch_bounds__(256) void place_kernel(
    const unsigned int* __restrict__ tmp, const int* __restrict__ bcnt,
    const int* __restrict__ offsets, int* __restrict__ src_sorted, int N)
{
    int b = blockIdx.x;
    __shared__ int cur[64];
    if (threadIdx.x < 64) {
        int node = (b << 6) + threadIdx.x;
        cur[threadIdx.x] = (node < N) ? offsets[node] : 0;
    }
    __syncthreads();
    int cnt = min(bcnt[b << 4], BKT_CAP);
    const unsigned int* tb = tmp + ((size_t)b << 11);
    for (int i = threadIdx.x; i < cnt; i += 256) {
        unsigned int p = tb[i];
        int pos = atomicAdd(&cur[p & 63u], 1);
        src_sorted[pos] = (int)(p >> 6);
    }
}

// ---------------------------------------------------------------------------
// Fused GAT aggregation (per-node gather, zero atomics), bf16 h.
// ---------------------------------------------------------------------------
__device__ __forceinline__ void fma8(const uint4& p, float w, float* a) {
    a[0] += w * bflo(p.x); a[1] += w * bfhi(p.x);
    a[2] += w * bflo(p.y); a[3] += w * bfhi(p.y);
    a[4] += w * bflo(p.z); a[5] += w * bfhi(p.z);
    a[6] += w * bflo(p.w); a[7] += w * bfhi(p.w);
}

template <int Hh, int Cc, bool DO_ELU>
__global__ __launch_bounds__(256) void gat_agg_kernel(
    const int* __restrict__ offsets, const int* __restrict__ src_sorted,
    const unsigned short* __restrict__ h, const float* __restrict__ alsrc,
    const float* __restrict__ aldst, const float* __restrict__ bias,
    float* __restrict__ outf, int N)
{
    constexpr int HC  = Hh * Cc;
    constexpr int TPN = HC / 8;
    constexpr int NPB = 256 / TPN;
    constexpr int CHUNK = 64;
    __shared__ int   s_src[NPB][CHUNK];
    __shared__ __align__(16) float s_w[NPB][CHUNK][Hh];
    __shared__ int   s_nch[NPB];

    const int g  = threadIdx.x / TPN;
    const int lt = threadIdx.x % TPN;
    const int n  = blockIdx.x * NPB + g;
    const bool valid = n < N;

    int off0 = 0, deg = 0;
    if (valid) { off0 = offsets[n]; deg = offsets[n + 1] - off0; }
    if (lt == 0) s_nch[g] = (deg + CHUNK - 1) / CHUNK;
    __syncthreads();
    int maxch = 0;
#pragma unroll
    for (int i = 0; i < NPB; ++i) maxch = max(maxch, s_nch[i]);

    const int hh = (lt * 8) / Cc;
    float adv[Hh];
    if (valid) {
        if constexpr (Hh == 4) {
            float4 t = ((const float4*)aldst)[n];
            adv[0] = t.x; adv[1] = t.y; adv[2] = t.z; adv[3] = t.w;
        } else {
            adv[0] = aldst[n];
        }
    }

    const uint4* h4 = (const uint4*)h;

    float a[8] = {0.f, 0.f, 0.f, 0.f, 0.f, 0.f, 0.f, 0.f};
    float den = 0.f;
    for (int ch = 0; ch < maxch; ++ch) {
        int base = ch * CHUNK;
        int cnt = deg - base;
        cnt = cnt < 0 ? 0 : (cnt > CHUNK ? CHUNK : cnt);
        __syncthreads();
        for (int i = lt; i < cnt; i += TPN) {
            int s = src_sorted[off0 + base + i];
            s_src[g][i] = s;
            if constexpr (Hh == 4) {
                float4 av = ((const float4*)alsrc)[s];
                ((float4*)&s_w[g][i][0])[0] = make_float4(
                    __expf(lrelu(av.x + adv[0])), __expf(lrelu(av.y + adv[1])),
                    __expf(lrelu(av.z + adv[2])), __expf(lrelu(av.w + adv[3])));
            } else {
                s_w[g][i][0] = __expf(lrelu(alsrc[s] + adv[0]));
            }
        }
        __syncthreads();
        int i = 0;
        for (; i + 1 < cnt; i += 2) {
            int s0 = s_src[g][i], s1 = s_src[g][i + 1];
            float w0 = s_w[g][i][hh], w1 = s_w[g][i + 1][hh];
            uint4 p0 = h4[(size_t)s0 * TPN + lt];
            uint4 p1 = h4[(size_t)s1 * TPN + lt];
            fma8(p0, w0, a);
            fma8(p1, w1, a);
            den += w0 + w1;
        }
        if (i < cnt) {
            int s0 = s_src[g][i];
            float w0 = s_w[g][i][hh];
            uint4 p0 = h4[(size_t)s0 * TPN + lt];
            fma8(p0, w0, a);
            den += w0;
        }
    }

    if (valid) {
        float wself = __expf(lrelu(alsrc[n * Hh + hh] + adv[hh]));
        uint4 p = h4[(size_t)n * TPN + lt];
        fma8(p, wself, a);
        den += wself + 1e-16f;
        float inv = 1.f / den;
        float4 bv0 = ((const float4*)bias)[lt * 2];
        float4 bv1 = ((const float4*)bias)[lt * 2 + 1];
        float o[8];
        o[0] = a[0] * inv + bv0.x; o[1] = a[1] * inv + bv0.y;
        o[2] = a[2] * inv + bv0.z; o[3] = a[3] * inv + bv0.w;
        o[4] = a[4] * inv + bv1.x; o[5] = a[5] * inv + bv1.y;
        o[6] = a[6] * inv + bv1.z; o[7] = a[7] * inv + bv1.w;
        if (DO_ELU) {
#pragma unroll
            for (int q = 0; q < 8; ++q)
                o[q] = o[q] > 0.f ? o[q] : __expf(o[q]) - 1.f;
        }
        float4* op = (float4*)(outf + (size_t)n * HC);
        op[lt * 2]     = make_float4(o[0], o[1], o[2], o[3]);
        op[lt * 2 + 1] = make_float4(o[4], o[5], o[6], o[7]);
    }
}

// ---------------------------------------------------------------------------
// classification head: out[n,k] = h3[n,:] @ Wc[:,k] + bc[k]   (32 -> 2)
// ---------------------------------------------------------------------------
__global__ __launch_bounds__(256) void head_kernel(
    const float* __restrict__ h3, const float* __restrict__ Wc,
    const float* __restrict__ bc, float* __restrict__ out, int N)
{
    int t = blockIdx.x * 256 + threadIdx.x;
    int n = t / 2, k = t % 2;
    if (n >= N) return;
    float s = bc[k];
#pragma unroll
    for (int c = 0; c < 32; ++c) s += h3[(size_t)n * 32 + c] * Wc[c * 2 + k];
    out[(size_t)n * 2 + k] = s;
}

extern "C" void kernel_launch(void* const* d_in, const int* in_sizes, int n_in,
                              void* d_out, int out_size, void* d_ws, size_t ws_size,
                              hipStream_t stream)
{
    const float* x   = (const float*)d_in[0];
    const int*   ei  = (const int*)d_in[1];
    const float* W1  = (const float*)d_in[2];
    const float* a1s = (const float*)d_in[3];
    const float* a1d = (const float*)d_in[4];
    const float* b1  = (const float*)d_in[5];
    const float* W2  = (const float*)d_in[6];
    const float* a2s = (const float*)d_in[7];
    const float* a2d = (const float*)d_in[8];
    const float* b2  = (const float*)d_in[9];
    const float* W3  = (const float*)d_in[10];
    const float* a3s = (const float*)d_in[11];
    const float* a3d = (const float*)d_in[12];
    const float* b3  = (const float*)d_in[13];
    const float* Wc  = (const float*)d_in[14];
    const float* bc  = (const float*)d_in[15];

    const int N = in_sizes[0] / 128;
    const int E = in_sizes[1] / 2;
    const int* srcIdx = ei;
    const int* dstIdx = ei + E;

    const int NBKT = (N + 63) >> 6;

    float* ws    = (float*)d_ws;
    float* fbuf  = ws;                                  // N*128 fp32
    float* alsrc = fbuf + (size_t)N * 128;              // N*4
    float* aldst = alsrc + (size_t)N * 4;               // N*4
    unsigned short* hbuf = (unsigned short*)(aldst + (size_t)N * 4); // N*128 bf16
    int* deg        = (int*)(hbuf + (size_t)N * 128);   // N
    int* offsets    = deg + N;                          // N+1
    int* src_sorted = offsets + N + 1;                  // E
    int* blocksums  = src_sorted + E;                   // 64
    int* blockbase  = blocksums + 64;                   // 64
    uintptr_t wp = ((uintptr_t)(blockbase + 64) + 15) & ~(uintptr_t)15;
    unsigned short* wt1 = (unsigned short*)wp;          // 16384 bf16, 16B-aligned
    unsigned short* wt2 = wt1 + 16384;                  // 16384 bf16
    int* bcnt       = (int*)(wt2 + 16384);              // NBKT*16 (64B-strided)
    unsigned int* tmp = (unsigned int*)(bcnt + (size_t)NBKT * 16); // NBKT*BKT_CAP

    float* node_out = (float*)d_out;                    // N*2
    float* link_out = node_out + (size_t)N * 2;         // N*32

    const int nb = (N + 4095) / 4096;
    const int nbBin = (E + CH_BIN - 1) / CH_BIN;

    // ---------------- W pre-transpose (bf16) + CSR build --------------------
    wtrans_kernel<<<128, 256, 0, stream>>>(W1, W2, wt1, wt2);
    hipMemsetAsync(bcnt, 0, (size_t)NBKT * 16 * sizeof(int), stream);
    bin_kernel<<<nbBin, 1024, 0, stream>>>(srcIdx, dstIdx, bcnt, tmp, E, NBKT);
    hist_kernel<<<NBKT, 256, 0, stream>>>(tmp, bcnt, deg, N);
    block_sum_kernel<<<nb, 256, 0, stream>>>(deg, blocksums, N);
    scan_sums_kernel<<<1, 64, 0, stream>>>(blocksums, blockbase, offsets + N, nb);
    scan_final_kernel<<<nb, 256, 0, stream>>>(deg, blockbase, offsets, N);
    place_kernel<<<NBKT, 256, 0, stream>>>(tmp, bcnt, offsets, src_sorted, N);

    // ---------------- layer 1 (IN=128 -> H=4,C=32, concat, ELU) -------------
    transform_mfma_kernel<<<(N + 63) / 64, 256, 0, stream>>>(
        x, wt1, a1s, a1d, hbuf, alsrc, aldst, N);
    gat_agg_kernel<4, 32, true><<<(N + 15) / 16, 256, 0, stream>>>(
        offsets, src_sorted, hbuf, alsrc, aldst, b1, fbuf, N);

    // ---------------- layer 2 (128 -> H=4,C=32, concat, ELU) ----------------
    transform_mfma_kernel<<<(N + 63) / 64, 256, 0, stream>>>(
        fbuf, wt2, a2s, a2d, hbuf, alsrc, aldst, N);
    gat_agg_kernel<4, 32, true><<<(N + 15) / 16, 256, 0, stream>>>(
        offsets, src_sorted, hbuf, alsrc, aldst, b2, fbuf, N);

    // ---------------- layer 3 (128 -> H=1,C=32, no concat, no ELU) ----------
    transform_kernel<32, 1, 4><<<(N + 127) / 128, 256, 0, stream>>>(
        fbuf, W3, a3s, a3d, hbuf, alsrc, aldst, N);
    gat_agg_kernel<1, 32, false><<<(N + 63) / 64, 256, 0, stream>>>(
        offsets, src_sorted, hbuf, alsrc, aldst, b3, link_out, N);

    // ---------------- head: node_output = h3 @ Wc + bc ----------------------
    head_kernel<<<(N * 2 + 255) / 256, 256, 0, stream>>>(link_out, Wc, bc, node_out, N);
}

// Round 14
// 272.673 us; speedup vs baseline: 1.3692x; 1.0837x over previous
//
#include <hip/hip_runtime.h>
#include <math.h>

#define SLOPE 0.2f

__device__ __forceinline__ float lrelu(float x) { return x > 0.f ? x : SLOPE * x; }

// bf16 helpers
__device__ __forceinline__ float bflo(unsigned int u) { return __uint_as_float(u << 16); }
__device__ __forceinline__ float bfhi(unsigned int u) { return __uint_as_float(u & 0xffff0000u); }
__device__ __forceinline__ unsigned short f2bf(float f) {   // round-nearest-even
    unsigned int u = __float_as_uint(f);
    unsigned int r = u + 0x7fffu + ((u >> 16) & 1u);
    return (unsigned short)(r >> 16);
}

typedef short frag8 __attribute__((ext_vector_type(8)));   // 8 bf16 (4 VGPR)
typedef float f32x4 __attribute__((ext_vector_type(4)));   // MFMA acc

// ---------------------------------------------------------------------------
// One-off: Wt[n][k] = bf16(W[k][n]) for W1 and W2 (128x128 each).
// ---------------------------------------------------------------------------
__global__ __launch_bounds__(256) void wtrans_kernel(
    const float* __restrict__ W1, const float* __restrict__ W2,
    unsigned short* __restrict__ Wt1, unsigned short* __restrict__ Wt2)
{
    int idx = blockIdx.x * 256 + threadIdx.x;   // grid 128 -> 32768
    const float* W = W1;
    unsigned short* Wt = Wt1;
    int i = idx;
    if (idx >= 16384) { W = W2; Wt = Wt2; i = idx - 16384; }
    int n = i >> 7, k = i & 127;
    Wt[i] = f2bf(W[k * 128 + n]);
}

// ---------------------------------------------------------------------------
// MFMA transform for layers 1-2 (CIN=128 -> COUT=128, H=4), input fp32 or
// bf16 (templated). h = bf16(x) @ bf16(W), fp32 acc, mfma_f32_16x16x32_bf16.
// Block: 64 nodes x 128 cols, 4 waves; wave w = head w, 8 acc tiles.
// Logits from fp32 accumulators via shfl; h out via LDS transpose.
// ---------------------------------------------------------------------------
template <bool BF16IN>
__global__ __launch_bounds__(256) void transform_mfma_kernel(
    const void* __restrict__ xin, const unsigned short* __restrict__ Wt,
    const float* __restrict__ a_src, const float* __restrict__ a_dst,
    unsigned short* __restrict__ hout, float* __restrict__ alsrc,
    float* __restrict__ aldst, int N)
{
    constexpr int MB = 64;               // nodes per block
    constexpr int LDK = 136;             // padded row (bf16)
    __shared__ __align__(16) unsigned short xs[MB * LDK];    // x tile / h tile
    __shared__ __align__(16) unsigned short wt[128 * LDK];   // Wt[n][k]

    const int node0 = blockIdx.x * MB;
    const int t = threadIdx.x;

    if constexpr (BF16IN) {
        const unsigned short* xb = (const unsigned short*)xin;
        for (int i = t; i < MB * 16; i += 256) {         // 16 uint4 per row
            int row = i >> 4, c16 = i & 15;
            uint4 v = make_uint4(0u, 0u, 0u, 0u);
            if (node0 + row < N)
                v = ((const uint4*)(xb + (size_t)(node0 + row) * 128))[c16];
            *(uint4*)&xs[row * LDK + c16 * 8] = v;
        }
    } else {
        const float* xf = (const float*)xin;
        for (int i = t; i < MB * 32; i += 256) {
            int row = i >> 5, col4 = i & 31;
            ushort4 o;
            if (node0 + row < N) {
                float4 v = ((const float4*)(xf + (size_t)(node0 + row) * 128))[col4];
                o.x = f2bf(v.x); o.y = f2bf(v.y); o.z = f2bf(v.z); o.w = f2bf(v.w);
            } else {
                o.x = o.y = o.z = o.w = 0;
            }
            *(ushort4*)&xs[row * LDK + col4 * 4] = o;
        }
    }
    for (int i = t; i < 2048; i += 256) {                // Wt: 2048 x 16B
        int n = i >> 4, k16 = i & 15;
        uint4 v = ((const uint4*)Wt)[i];
        *(uint4*)&wt[n * LDK + k16 * 8] = v;
    }
    __syncthreads();

    const int w    = t >> 6;             // wave = head
    const int lane = t & 63;
    const int r    = lane & 15;
    const int q    = lane >> 4;

    f32x4 acc[4][2];
#pragma unroll
    for (int mt = 0; mt < 4; ++mt)
#pragma unroll
        for (int nl = 0; nl < 2; ++nl)
            acc[mt][nl] = (f32x4){0.f, 0.f, 0.f, 0.f};

#pragma unroll
    for (int kk = 0; kk < 4; ++kk) {
        const int kof = kk * 32 + q * 8;
        frag8 b0 = *(const frag8*)&wt[(w * 32 + r) * LDK + kof];
        frag8 b1 = *(const frag8*)&wt[(w * 32 + 16 + r) * LDK + kof];
#pragma unroll
        for (int mt = 0; mt < 4; ++mt) {
            frag8 a = *(const frag8*)&xs[(mt * 16 + r) * LDK + kof];
            acc[mt][0] = __builtin_amdgcn_mfma_f32_16x16x32_bf16(a, b0, acc[mt][0], 0, 0, 0);
            acc[mt][1] = __builtin_amdgcn_mfma_f32_16x16x32_bf16(a, b1, acc[mt][1], 0, 0, 0);
        }
    }

    // ---- logits from fp32 acc ----
    const float as0 = a_src[w * 32 + r],      ad0 = a_dst[w * 32 + r];
    const float as1 = a_src[w * 32 + 16 + r], ad1 = a_dst[w * 32 + 16 + r];
#pragma unroll
    for (int mt = 0; mt < 4; ++mt) {
#pragma unroll
        for (int reg = 0; reg < 4; ++reg) {
            float s = acc[mt][0][reg] * as0 + acc[mt][1][reg] * as1;
            float d = acc[mt][0][reg] * ad0 + acc[mt][1][reg] * ad1;
#pragma unroll
            for (int off = 1; off < 16; off <<= 1) {
                s += __shfl_xor(s, off);
                d += __shfl_xor(d, off);
            }
            if (r == 0) {
                int m = mt * 16 + q * 4 + reg;
                int n = node0 + m;
                if (n < N) {
                    alsrc[n * 4 + w] = s;
                    aldst[n * 4 + w] = d;
                }
            }
        }
    }

    // ---- h -> LDS (bf16, D-layout scatter), then coalesced global store ----
    __syncthreads();
#pragma unroll
    for (int mt = 0; mt < 4; ++mt)
#pragma unroll
        for (int nl = 0; nl < 2; ++nl)
#pragma unroll
            for (int reg = 0; reg < 4; ++reg) {
                int m = mt * 16 + q * 4 + reg;
                int n = w * 32 + nl * 16 + r;
                xs[m * LDK + n] = f2bf(acc[mt][nl][reg]);
            }
    __syncthreads();
    {
        int row = t >> 2, cbase = (t & 3) * 32;      // 4 threads/row, 32 bf16 each
        if (node0 + row < N) {
            uint4* dst = (uint4*)(hout + (size_t)(node0 + row) * 128 + cbase);
#pragma unroll
            for (int j = 0; j < 4; ++j)
                dst[j] = *(const uint4*)&xs[row * LDK + cbase + j * 8];
        }
    }
}

// ---------------------------------------------------------------------------
// VALU transform for layer 3 (CIN=128 bf16 -> COUT=32, H=1), fused logits.
// ---------------------------------------------------------------------------
template <int COUT, int Hh, int NPT>
__global__ __launch_bounds__(256) void transform_kernel(
    const unsigned short* __restrict__ xin, const float* __restrict__ W,
    const float* __restrict__ a_src, const float* __restrict__ a_dst,
    unsigned short* __restrict__ hout, float* __restrict__ alsrc,
    float* __restrict__ aldst, int N)
{
    constexpr int JT = COUT / 4;
    constexpr int GROUPS = 256 / JT;
    constexpr int NB = GROUPS * NPT;
    constexpr int PAD = 4;
    __shared__ __align__(16) float xs[NB][128 + PAD];

    const int node0 = blockIdx.x * NB;
    for (int i = threadIdx.x; i < NB * 16; i += 256) {   // 16 uint4/row (bf16)
        int row = i >> 4, c16 = i & 15;
        uint4 v = make_uint4(0u, 0u, 0u, 0u);
        if (node0 + row < N)
            v = ((const uint4*)(xin + (size_t)(node0 + row) * 128))[c16];
        float* xp = &xs[row][c16 * 8];
        xp[0] = bflo(v.x); xp[1] = bfhi(v.x);
        xp[2] = bflo(v.y); xp[3] = bfhi(v.y);
        xp[4] = bflo(v.z); xp[5] = bfhi(v.z);
        xp[6] = bflo(v.w); xp[7] = bfhi(v.w);
    }
    __syncthreads();

    const int jt = threadIdx.x % JT;
    const int g  = threadIdx.x / JT;
    const int j4 = jt * 4;

    float4 acc[NPT];
#pragma unroll
    for (int m = 0; m < NPT; ++m) acc[m] = make_float4(0.f, 0.f, 0.f, 0.f);

    const float4* Wf4 = (const float4*)W;
    for (int k4 = 0; k4 < 32; ++k4) {
        float4 w0 = Wf4[(4 * k4 + 0) * JT + jt];
        float4 w1 = Wf4[(4 * k4 + 1) * JT + jt];
        float4 w2 = Wf4[(4 * k4 + 2) * JT + jt];
        float4 w3 = Wf4[(4 * k4 + 3) * JT + jt];
#pragma unroll
        for (int m = 0; m < NPT; ++m) {
            float4 xv = *(const float4*)&xs[g * NPT + m][k4 << 2];
            acc[m].x += xv.x * w0.x + xv.y * w1.x + xv.z * w2.x + xv.w * w3.x;
            acc[m].y += xv.x * w0.y + xv.y * w1.y + xv.z * w2.y + xv.w * w3.y;
            acc[m].z += xv.x * w0.z + xv.y * w1.z + xv.z * w2.z + xv.w * w3.z;
            acc[m].w += xv.x * w0.w + xv.y * w1.w + xv.z * w2.w + xv.w * w3.w;
        }
    }

    const float4 as4 = ((const float4*)a_src)[jt];
    const float4 ad4 = ((const float4*)a_dst)[jt];
    const int hh = j4 >> 5;

#pragma unroll
    for (int m = 0; m < NPT; ++m) {
        int n = node0 + g * NPT + m;
        float4 v = acc[m];
        float sv = v.x * as4.x + v.y * as4.y + v.z * as4.z + v.w * as4.w;
        float dv = v.x * ad4.x + v.y * ad4.y + v.z * ad4.z + v.w * ad4.w;
#pragma unroll
        for (int off = 4; off >= 1; off >>= 1) {
            sv += __shfl_xor(sv, off);
            dv += __shfl_xor(dv, off);
        }
        if (n < N) {
            ushort4 hp;
            hp.x = f2bf(v.x); hp.y = f2bf(v.y);
            hp.z = f2bf(v.z); hp.w = f2bf(v.w);
            ((ushort4*)(hout + (size_t)n * COUT))[jt] = hp;
            if ((jt & 7) == 0) {
                alsrc[n * Hh + hh] = sv;
                aldst[n * Hh + hh] = dv;
            }
        }
    }
}

// ---------------------------------------------------------------------------
// CSR build, bucket-local counting sort (64 dst nodes per bucket).
// bin: block-aggregated binning into per-bucket regions of tmp.
// bucket_csr: fused hist + local wave-scan + place. offsets are
// BUCKET-STRIDED (offsets[n] = b*2048 + local prefix); deg[] passed
// separately to gat_agg — no global scan needed.
// ---------------------------------------------------------------------------
#define BKT_CAP 2048
#define NBKT_MAX 1024
#define CH_BIN 4096

__global__ __launch_bounds__(1024) void bin_kernel(
    const int* __restrict__ src, const int* __restrict__ dst,
    int* __restrict__ bcnt, unsigned int* __restrict__ tmp, int E, int nbkt)
{
    __shared__ int hist[NBKT_MAX];
    __shared__ int base[NBKT_MAX];
    const int e0 = blockIdx.x * CH_BIN;
    const int e1 = min(e0 + CH_BIN, E);

    for (int b = threadIdx.x; b < nbkt; b += 1024) hist[b] = 0;
    __syncthreads();
    for (int e = e0 + threadIdx.x; e < e1; e += 1024) {
        int d = __builtin_nontemporal_load(dst + e);
        atomicAdd(&hist[d >> 6], 1);
    }
    __syncthreads();
    for (int b = threadIdx.x; b < nbkt; b += 1024) {
        int c = hist[b];
        base[b] = (c > 0) ? atomicAdd(&bcnt[b << 4], c) : 0;  // 64B-strided
        hist[b] = 0;
    }
    __syncthreads();
    for (int e = e0 + threadIdx.x; e < e1; e += 1024) {
        int d = __builtin_nontemporal_load(dst + e);
        int s = __builtin_nontemporal_load(src + e);
        int b = d >> 6;
        int pos = base[b] + atomicAdd(&hist[b], 1);
        if (pos < BKT_CAP)
            tmp[((size_t)b << 11) + pos] =
                ((unsigned int)s << 6) | (unsigned int)(d & 63);
    }
}

__global__ __launch_bounds__(256) void bucket_csr_kernel(
    const unsigned int* __restrict__ tmp, const int* __restrict__ bcnt,
    int* __restrict__ deg, int* __restrict__ offsets,
    int* __restrict__ src_sorted, int N)
{
    int b = blockIdx.x;
    __shared__ int hist[64];
    if (threadIdx.x < 64) hist[threadIdx.x] = 0;
    __syncthreads();
    int cnt = min(bcnt[b << 4], BKT_CAP);
    const unsigned int* tb = tmp + ((size_t)b << 11);
    for (int i = threadIdx.x; i < cnt; i += 256)
        atomicAdd(&hist[tb[i] & 63u], 1);
    __syncthreads();
    if (threadIdx.x < 64) {                          // wave 0: 64-wide scan
        int v = hist[threadIdx.x];
        int incl = v;
#pragma unroll
        for (int off = 1; off < 64; off <<= 1) {
            int t2 = __shfl_up(incl, off);
            if (threadIdx.x >= off) incl += t2;
        }
        int excl = incl - v;
        int node = (b << 6) + threadIdx.x;
        if (node < N) {
            deg[node] = v;
            offsets[node] = (b << 11) + excl;
        }
        hist[threadIdx.x] = excl;                    // reuse as cursor
    }
    __syncthreads();
    for (int i = threadIdx.x; i < cnt; i += 256) {
        unsigned int p = tb[i];
        int pos = atomicAdd(&hist[p & 63u], 1);
        src_sorted[((size_t)b << 11) + pos] = (int)(p >> 6);
    }
}

// ---------------------------------------------------------------------------
// Fused GAT aggregation (per-node gather, zero atomics), bf16 h.
// 8 channels/thread (16B uint4 per edge/thread), x2 unrolled.
// OUTBF: write bf16 activations (layers 1-2). FUSE_HEAD: layer-3 head fused
// (out = fp32 link_out + node_out via 4-lane shfl dot with Wc).
// ---------------------------------------------------------------------------
__device__ __forceinline__ void fma8(const uint4& p, float w, float* a) {
    a[0] += w * bflo(p.x); a[1] += w * bfhi(p.x);
    a[2] += w * bflo(p.y); a[3] += w * bfhi(p.y);
    a[4] += w * bflo(p.z); a[5] += w * bfhi(p.z);
    a[6] += w * bflo(p.w); a[7] += w * bfhi(p.w);
}

template <int Hh, int Cc, bool DO_ELU, bool OUTBF, bool FUSE_HEAD>
__global__ __launch_bounds__(256) void gat_agg_kernel(
    const int* __restrict__ offsets, const int* __restrict__ deg_arr,
    const int* __restrict__ src_sorted,
    const unsigned short* __restrict__ h, const float* __restrict__ alsrc,
    const float* __restrict__ aldst, const float* __restrict__ bias,
    void* __restrict__ outv, const float* __restrict__ Wc,
    const float* __restrict__ bc, float* __restrict__ node_out, int N)
{
    constexpr int HC  = Hh * Cc;
    constexpr int TPN = HC / 8;
    constexpr int NPB = 256 / TPN;
    constexpr int CHUNK = 64;
    __shared__ int   s_src[NPB][CHUNK];
    __shared__ __align__(16) float s_w[NPB][CHUNK][Hh];
    __shared__ int   s_nch[NPB];

    const int g  = threadIdx.x / TPN;
    const int lt = threadIdx.x % TPN;
    const int n  = blockIdx.x * NPB + g;
    const bool valid = n < N;

    int off0 = 0, deg = 0;
    if (valid) { off0 = offsets[n]; deg = deg_arr[n]; }
    if (lt == 0) s_nch[g] = (deg + CHUNK - 1) / CHUNK;
    __syncthreads();
    int maxch = 0;
#pragma unroll
    for (int i = 0; i < NPB; ++i) maxch = max(maxch, s_nch[i]);

    const int hh = (lt * 8) / Cc;
    float adv[Hh];
    if (valid) {
        if constexpr (Hh == 4) {
            float4 t = ((const float4*)aldst)[n];
            adv[0] = t.x; adv[1] = t.y; adv[2] = t.z; adv[3] = t.w;
        } else {
            adv[0] = aldst[n];
        }
    }

    const uint4* h4 = (const uint4*)h;

    float a[8] = {0.f, 0.f, 0.f, 0.f, 0.f, 0.f, 0.f, 0.f};
    float den = 0.f;
    for (int ch = 0; ch < maxch; ++ch) {
        int base = ch * CHUNK;
        int cnt = deg - base;
        cnt = cnt < 0 ? 0 : (cnt > CHUNK ? CHUNK : cnt);
        __syncthreads();
        for (int i = lt; i < cnt; i += TPN) {
            int s = src_sorted[off0 + base + i];
            s_src[g][i] = s;
            if constexpr (Hh == 4) {
                float4 av = ((const float4*)alsrc)[s];
                ((float4*)&s_w[g][i][0])[0] = make_float4(
                    __expf(lrelu(av.x + adv[0])), __expf(lrelu(av.y + adv[1])),
                    __expf(lrelu(av.z + adv[2])), __expf(lrelu(av.w + adv[3])));
            } else {
                s_w[g][i][0] = __expf(lrelu(alsrc[s] + adv[0]));
            }
        }
        __syncthreads();
        int i = 0;
        for (; i + 1 < cnt; i += 2) {
            int s0 = s_src[g][i], s1 = s_src[g][i + 1];
            float w0 = s_w[g][i][hh], w1 = s_w[g][i + 1][hh];
            uint4 p0 = h4[(size_t)s0 * TPN + lt];
            uint4 p1 = h4[(size_t)s1 * TPN + lt];
            fma8(p0, w0, a);
            fma8(p1, w1, a);
            den += w0 + w1;
        }
        if (i < cnt) {
            int s0 = s_src[g][i];
            float w0 = s_w[g][i][hh];
            uint4 p0 = h4[(size_t)s0 * TPN + lt];
            fma8(p0, w0, a);
            den += w0;
        }
    }

    if (valid) {
        float wself = __expf(lrelu(alsrc[n * Hh + hh] + adv[hh]));
        uint4 p = h4[(size_t)n * TPN + lt];
        fma8(p, wself, a);
        den += wself + 1e-16f;
        float inv = 1.f / den;
        float4 bv0 = ((const float4*)bias)[lt * 2];
        float4 bv1 = ((const float4*)bias)[lt * 2 + 1];
        float o[8];
        o[0] = a[0] * inv + bv0.x; o[1] = a[1] * inv + bv0.y;
        o[2] = a[2] * inv + bv0.z; o[3] = a[3] * inv + bv0.w;
        o[4] = a[4] * inv + bv1.x; o[5] = a[5] * inv + bv1.y;
        o[6] = a[6] * inv + bv1.z; o[7] = a[7] * inv + bv1.w;
        if (DO_ELU) {
#pragma unroll
            for (int q = 0; q < 8; ++q)
                o[q] = o[q] > 0.f ? o[q] : __expf(o[q]) - 1.f;
        }
        if constexpr (OUTBF) {
            unsigned short* ob = (unsigned short*)outv;
            uint4 pk;
            pk.x = (unsigned int)f2bf(o[0]) | ((unsigned int)f2bf(o[1]) << 16);
            pk.y = (unsigned int)f2bf(o[2]) | ((unsigned int)f2bf(o[3]) << 16);
            pk.z = (unsigned int)f2bf(o[4]) | ((unsigned int)f2bf(o[5]) << 16);
            pk.w = (unsigned int)f2bf(o[6]) | ((unsigned int)f2bf(o[7]) << 16);
            ((uint4*)(ob + (size_t)n * HC))[lt] = pk;
        } else {
            float* of = (float*)outv;
            float4* op = (float4*)(of + (size_t)n * HC);
            op[lt * 2]     = make_float4(o[0], o[1], o[2], o[3]);
            op[lt * 2 + 1] = make_float4(o[4], o[5], o[6], o[7]);
        }
        if constexpr (FUSE_HEAD) {
            // node_out[n,k] = sum_c o_full[c]*Wc[c,k] + bc[k], k in {0,1}
            float s0 = 0.f, s1 = 0.f;
#pragma unroll
            for (int q = 0; q < 8; ++q) {
                int c = lt * 8 + q;
                s0 += o[q] * Wc[c * 2];
                s1 += o[q] * Wc[c * 2 + 1];
            }
            s0 += __shfl_xor(s0, 1); s0 += __shfl_xor(s0, 2);
            s1 += __shfl_xor(s1, 1); s1 += __shfl_xor(s1, 2);
            if (lt == 0) {
                node_out[(size_t)n * 2]     = s0 + bc[0];
                node_out[(size_t)n * 2 + 1] = s1 + bc[1];
            }
        }
    }
}

extern "C" void kernel_launch(void* const* d_in, const int* in_sizes, int n_in,
                              void* d_out, int out_size, void* d_ws, size_t ws_size,
                              hipStream_t stream)
{
    const float* x   = (const float*)d_in[0];
    const int*   ei  = (const int*)d_in[1];
    const float* W1  = (const float*)d_in[2];
    const float* a1s = (const float*)d_in[3];
    const float* a1d = (const float*)d_in[4];
    const float* b1  = (const float*)d_in[5];
    const float* W2  = (const float*)d_in[6];
    const float* a2s = (const float*)d_in[7];
    const float* a2d = (const float*)d_in[8];
    const float* b2  = (const float*)d_in[9];
    const float* W3  = (const float*)d_in[10];
    const float* a3s = (const float*)d_in[11];
    const float* a3d = (const float*)d_in[12];
    const float* b3  = (const float*)d_in[13];
    const float* Wc  = (const float*)d_in[14];
    const float* bc  = (const float*)d_in[15];

    const int N = in_sizes[0] / 128;
    const int E = in_sizes[1] / 2;
    const int* srcIdx = ei;
    const int* dstIdx = ei + E;

    const int NBKT = (N + 63) >> 6;

    // ws layout (16B-aligned where vector loads require it)
    float* alsrc = (float*)d_ws;                        // N*4
    float* aldst = alsrc + (size_t)N * 4;               // N*4
    unsigned short* fb16 = (unsigned short*)(aldst + (size_t)N * 4); // N*128 bf16
    unsigned short* hbuf = fb16 + (size_t)N * 128;      // N*128 bf16
    int* deg        = (int*)(hbuf + (size_t)N * 128);   // N
    int* offsets    = deg + N;                          // N
    uintptr_t wp = ((uintptr_t)(offsets + N) + 15) & ~(uintptr_t)15;
    unsigned short* wt1 = (unsigned short*)wp;          // 16384 bf16, 16B-aligned
    unsigned short* wt2 = wt1 + 16384;                  // 16384 bf16
    int* bcnt       = (int*)(wt2 + 16384);              // NBKT*16 (64B-strided)
    int* src_sorted = bcnt + (size_t)NBKT * 16;         // NBKT*BKT_CAP
    unsigned int* tmp = (unsigned int*)(src_sorted + (size_t)NBKT * BKT_CAP);

    float* node_out = (float*)d_out;                    // N*2
    float* link_out = node_out + (size_t)N * 2;         // N*32

    const int nbBin = (E + CH_BIN - 1) / CH_BIN;

    // ---------------- W pre-transpose (bf16) + CSR build --------------------
    wtrans_kernel<<<128, 256, 0, stream>>>(W1, W2, wt1, wt2);
    hipMemsetAsync(bcnt, 0, (size_t)NBKT * 16 * sizeof(int), stream);
    bin_kernel<<<nbBin, 1024, 0, stream>>>(srcIdx, dstIdx, bcnt, tmp, E, NBKT);
    bucket_csr_kernel<<<NBKT, 256, 0, stream>>>(tmp, bcnt, deg, offsets, src_sorted, N);

    // ---------------- layer 1 (IN=128 fp32 -> H=4,C=32, concat, ELU) --------
    transform_mfma_kernel<false><<<(N + 63) / 64, 256, 0, stream>>>(
        x, wt1, a1s, a1d, hbuf, alsrc, aldst, N);
    gat_agg_kernel<4, 32, true, true, false><<<(N + 15) / 16, 256, 0, stream>>>(
        offsets, deg, src_sorted, hbuf, alsrc, aldst, b1, fb16,
        nullptr, nullptr, nullptr, N);

    // ---------------- layer 2 (128 bf16 -> H=4,C=32, concat, ELU) -----------
    transform_mfma_kernel<true><<<(N + 63) / 64, 256, 0, stream>>>(
        fb16, wt2, a2s, a2d, hbuf, alsrc, aldst, N);
    gat_agg_kernel<4, 32, true, true, false><<<(N + 15) / 16, 256, 0, stream>>>(
        offsets, deg, src_sorted, hbuf, alsrc, aldst, b2, fb16,
        nullptr, nullptr, nullptr, N);

    // ---------------- layer 3 (128 bf16 -> H=1,C=32) + fused head -----------
    transform_kernel<32, 1, 4><<<(N + 127) / 128, 256, 0, stream>>>(
        fb16, W3, a3s, a3d, hbuf, alsrc, aldst, N);
    gat_agg_kernel<1, 32, false, false, true><<<(N + 63) / 64, 256, 0, stream>>>(
        offsets, deg, src_sorted, hbuf, alsrc, aldst, b3, link_out,
        Wc, bc, node_out, N);
}